// Round 2
// baseline (1921.627 us; speedup 1.0000x reference)
//
#include <hip/hip_runtime.h>
#include <hip/hip_bf16.h>

#define DDIM 1024
#define NEXP 8
#define RANK 64
#define SCALING 2.0f

// One block (256 threads) per token. All tensors are float32 (per the
// reference); round-1's NaN came from misreading f32 buffers as bf16.
__global__ __launch_bounds__(256) void moe_lora_tok(
    const float* __restrict__ x,
    const float* __restrict__ Wg,
    const float* __restrict__ bg,
    const float* __restrict__ W1,
    const float* __restrict__ W2,
    float* __restrict__ out)
{
    const int t   = blockIdx.x;
    const int tid = threadIdx.x;

    __shared__ float xs[DDIM];
    __shared__ float logits[NEXP];
    __shared__ float hbuf[RANK];
    __shared__ int   sel_e[2];
    __shared__ float sel_g[2];

    // ---- load x[t] into LDS (each thread: one 16B float4 load) ----
    {
        float4 s = reinterpret_cast<const float4*>(x + (size_t)t * DDIM)[tid];
        xs[4 * tid + 0] = s.x;
        xs[4 * tid + 1] = s.y;
        xs[4 * tid + 2] = s.z;
        xs[4 * tid + 3] = s.w;
    }
    __syncthreads();

    // ---- router: wave w handles experts w and w+4 ----
    const int wave = tid >> 6;
    const int lane = tid & 63;
    for (int e = wave; e < NEXP; e += 4) {
        float acc = 0.f;
        const float* wr = Wg + (size_t)e * DDIM;
        for (int d = lane; d < DDIM; d += 64) acc += xs[d] * wr[d];
        #pragma unroll
        for (int off = 32; off > 0; off >>= 1) acc += __shfl_down(acc, off);
        if (lane == 0) logits[e] = acc + bg[e];
    }
    __syncthreads();

    // ---- top-2 + softmax-of-2 (jax.lax.top_k tie-break: lower index first) ----
    if (tid == 0) {
        int e0 = 0;
        for (int e = 1; e < NEXP; ++e) if (logits[e] > logits[e0]) e0 = e;
        int e1 = -1;
        for (int e = 0; e < NEXP; ++e) {
            if (e == e0) continue;
            if (e1 < 0 || logits[e] > logits[e1]) e1 = e;
        }
        float l0 = logits[e0], l1 = logits[e1];
        float g0 = 1.f / (1.f + expf(l1 - l0));   // l0 >= l1, numerically stable
        sel_e[0] = e0; sel_e[1] = e1;
        sel_g[0] = g0 * SCALING;
        sel_g[1] = (1.f - g0) * SCALING;
    }
    __syncthreads();

    float acc_out[4] = {0.f, 0.f, 0.f, 0.f};
    const int r   = tid >> 2;   // fc1 row 0..63
    const int sub = tid & 3;    // quarter of D handled by this thread

    for (int k = 0; k < 2; ++k) {
        const int   e = sel_e[k];
        const float g = sel_g[k];

        // ---- fc1: h[r] = gelu(dot(x, W1[e][r][:])) ; 4 threads per row ----
        {
            float acc = 0.f;
            const float4* w1p = reinterpret_cast<const float4*>(
                W1 + ((size_t)(e * RANK + r)) * DDIM + sub * 256);
            const float* xp = xs + sub * 256;
            #pragma unroll 8
            for (int j = 0; j < 64; ++j) {
                float4 s = w1p[j];
                acc += xp[4 * j + 0] * s.x + xp[4 * j + 1] * s.y
                     + xp[4 * j + 2] * s.z + xp[4 * j + 3] * s.w;
            }
            // reduce across the 4 sub-threads (same wave: lanes 4r..4r+3)
            acc += __shfl_xor(acc, 1);
            acc += __shfl_xor(acc, 2);
            if (sub == 0) {
                // exact gelu: 0.5*a*(1+erf(a/sqrt(2)))
                hbuf[r] = 0.5f * acc * (1.f + erff(acc * 0.70710678118654752f));
            }
        }
        __syncthreads();

        // ---- fc2: thread owns d = 4*tid .. 4*tid+3 ; y[d] = dot(h, W2[e][d][:]) ----
        {
            const float* w2base = W2 + ((size_t)e * DDIM + 4 * tid) * RANK;
            #pragma unroll
            for (int j = 0; j < 4; ++j) {
                const float4* wp = reinterpret_cast<const float4*>(w2base + (size_t)j * RANK);
                float acc = 0.f;
                #pragma unroll 4
                for (int i = 0; i < 16; ++i) {
                    float4 s = wp[i];
                    acc += hbuf[4 * i + 0] * s.x + hbuf[4 * i + 1] * s.y
                         + hbuf[4 * i + 2] * s.z + hbuf[4 * i + 3] * s.w;
                }
                acc_out[j] += g * acc;
            }
        }
        __syncthreads();   // protect hbuf before next expert overwrites it
    }

    // ---- store out[t][4*tid .. 4*tid+3] as one 16B float4 store ----
    float4 o;
    o.x = acc_out[0];
    o.y = acc_out[1];
    o.z = acc_out[2];
    o.w = acc_out[3];
    reinterpret_cast<float4*>(out + (size_t)t * DDIM)[tid] = o;
}

extern "C" void kernel_launch(void* const* d_in, const int* in_sizes, int n_in,
                              void* d_out, int out_size, void* d_ws, size_t ws_size,
                              hipStream_t stream) {
    const float* x  = (const float*)d_in[0];
    const float* Wg = (const float*)d_in[1];
    const float* bg = (const float*)d_in[2];
    const float* W1 = (const float*)d_in[3];
    const float* W2 = (const float*)d_in[4];
    float* out = (float*)d_out;

    const int N = in_sizes[0] / DDIM;   // B*S = 16384 tokens
    moe_lora_tok<<<N, 256, 0, stream>>>(x, Wg, bg, W1, W2, out);
}

// Round 3
// 812.817 us; speedup vs baseline: 2.3642x; 2.3642x over previous
//
#include <hip/hip_runtime.h>

#define DIMD 1024
#define NEXP 8
#define RNK  64
#define SCAL 2.0f
#define BK   128
#define XS_STR 132   // BK + 4 pad  -> balanced b128 LDS reads
#define HG_STR 68    // 64 + 4 pad
#define TR_STR 17    // 16 + 1 pad

// ---------------- Kernel 1: router + per-expert token gather ----------------
// block = 256 threads (4 waves), each wave handles one token at a time, 32
// tokens per block. Per-expert counts aggregated in LDS -> 8 global atomics.
__global__ __launch_bounds__(256) void router_kernel(
    const float* __restrict__ x, const float* __restrict__ Wg,
    const float* __restrict__ bg,
    int* __restrict__ counts, int* __restrict__ lists, float* __restrict__ gates,
    int N)
{
    const int tid  = threadIdx.x;
    const int wave = tid >> 6;
    const int lane = tid & 63;

    __shared__ int   lcount[NEXP];
    __shared__ int   gbase[NEXP];
    __shared__ int   tk_e[32][2];
    __shared__ int   tk_s[32][2];
    __shared__ float tk_g[32][2];

    if (tid < NEXP) lcount[tid] = 0;
    __syncthreads();

    const int t0 = blockIdx.x * 32;

    for (int it = 0; it < 8; ++it) {
        const int i = it * 4 + wave;           // token slot within block
        const int t = t0 + i;
        if (t < N) {
            // lane covers 16 consecutive d of x[t]
            const float4* xp = reinterpret_cast<const float4*>(x + (size_t)t * DIMD + lane * 16);
            float4 xv[4];
            #pragma unroll
            for (int u = 0; u < 4; ++u) xv[u] = xp[u];

            float acc[NEXP];
            #pragma unroll
            for (int e = 0; e < NEXP; ++e) {
                const float4* wp = reinterpret_cast<const float4*>(Wg + (size_t)e * DIMD + lane * 16);
                float a = 0.f;
                #pragma unroll
                for (int u = 0; u < 4; ++u) {
                    float4 wv = wp[u];
                    a += xv[u].x*wv.x + xv[u].y*wv.y + xv[u].z*wv.z + xv[u].w*wv.w;
                }
                acc[e] = a;
            }
            #pragma unroll
            for (int off = 32; off > 0; off >>= 1) {
                #pragma unroll
                for (int e = 0; e < NEXP; ++e) acc[e] += __shfl_xor(acc[e], off);
            }
            if (lane == 0) {
                float lg[NEXP];
                #pragma unroll
                for (int e = 0; e < NEXP; ++e) lg[e] = acc[e] + bg[e];
                // top-2, jax.lax.top_k tie-break = lower index first
                int e0 = 0;
                #pragma unroll
                for (int e = 1; e < NEXP; ++e) if (lg[e] > lg[e0]) e0 = e;
                int e1 = -1;
                #pragma unroll
                for (int e = 0; e < NEXP; ++e) {
                    if (e == e0) continue;
                    if (e1 < 0 || lg[e] > lg[e1]) e1 = e;
                }
                float g0 = 1.f / (1.f + expf(lg[e1] - lg[e0]));   // stable: arg <= 0
                int s0 = atomicAdd(&lcount[e0], 1);
                int s1 = atomicAdd(&lcount[e1], 1);
                tk_e[i][0] = e0; tk_s[i][0] = s0; tk_g[i][0] = g0 * SCAL;
                tk_e[i][1] = e1; tk_s[i][1] = s1; tk_g[i][1] = (1.f - g0) * SCAL;
            }
        }
    }
    __syncthreads();
    if (tid < NEXP) gbase[tid] = atomicAdd(&counts[tid], lcount[tid]);
    __syncthreads();
    if (tid < 32 && (t0 + tid) < N) {
        #pragma unroll
        for (int k = 0; k < 2; ++k) {
            int e   = tk_e[tid][k];
            int pos = gbase[e] + tk_s[tid][k];
            lists[(size_t)e * N + pos] = t0 + tid;
            gates[(size_t)e * N + pos] = tk_g[tid][k];
        }
    }
}

// ---------------- Kernel 2: expert-grouped LoRA (fc1+gelu+fc2+scatter) -----
// block = (expert e, tile of 64 gathered tokens), 256 threads.
// Phase A: Hg[64 tok][64 r] = gate * gelu(X W1^T), lane=token, wave owns 16 rows,
//          W1 rows via wave-uniform (scalar) loads, X from LDS chunks.
// Phase B: per wave: 16 d-tiles of 16; dot over r from per-lane hg registers,
//          W2 rows scalar-loaded; transpose 64x16 via per-wave LDS; coalesced
//          atomicAdd into out.
__global__ __launch_bounds__(256) void expert_kernel(
    const float* __restrict__ x, const float* __restrict__ W1, const float* __restrict__ W2,
    const int* __restrict__ counts, const int* __restrict__ lists,
    const float* __restrict__ gates, float* __restrict__ out, int N, int EB)
{
    const int e     = blockIdx.x / EB;
    const int jt    = blockIdx.x % EB;
    const int start = jt * 64;
    int m = counts[e] - start;
    if (m <= 0) return;
    if (m > 64) m = 64;

    const int tid  = threadIdx.x;
    const int wu   = __builtin_amdgcn_readfirstlane(tid >> 6);  // wave id, provably uniform
    const int lane = tid & 63;

    __shared__ int   tokl[64];
    __shared__ float gl[64];
    __shared__ float Hgs[64 * HG_STR];
    __shared__ float XsTr[64 * XS_STR];   // phase A: X chunk; phase B: per-wave transpose bufs

    if (tid < 64) {
        int idx = (tid < m) ? (start + tid) : start;   // dummy -> token[0], gate 0
        tokl[tid] = lists[(size_t)e * N + idx];
        gl[tid]   = (tid < m) ? gates[(size_t)e * N + idx] : 0.f;
    }
    __syncthreads();

    // ---------------- Phase A ----------------
    float acc[16];
    #pragma unroll
    for (int i = 0; i < 16; ++i) acc[i] = 0.f;

    const int tt = tid >> 2;   // staging: token row
    const int q  = tid & 3;    // staging: 32-float quarter of BK

    for (int kc = 0; kc < DIMD / BK; ++kc) {
        // stage Xs[64][BK] (gathered rows), coalesced float4 global loads
        {
            const float4* src = reinterpret_cast<const float4*>(
                x + (size_t)tokl[tt] * DIMD + kc * BK + q * 32);
            float4* dst = reinterpret_cast<float4*>(&XsTr[tt * XS_STR + q * 32]);
            #pragma unroll
            for (int u = 0; u < 8; ++u) dst[u] = src[u];
        }
        __syncthreads();

        for (int s = 0; s < BK / 16; ++s) {
            float4 xv[4];
            #pragma unroll
            for (int u = 0; u < 4; ++u)
                xv[u] = *reinterpret_cast<const float4*>(&XsTr[lane * XS_STR + s * 16 + 4 * u]);
            #pragma unroll
            for (int rr = 0; rr < 16; ++rr) {
                // wave-uniform address -> scalar loads (broadcast, no VALU/LDS cost)
                const float4* wr = reinterpret_cast<const float4*>(
                    W1 + ((size_t)(e * RNK + wu * 16 + rr)) * DIMD + kc * BK + s * 16);
                float a = acc[rr];
                #pragma unroll
                for (int u = 0; u < 4; ++u) {
                    float4 wv = wr[u];
                    a += xv[u].x*wv.x + xv[u].y*wv.y + xv[u].z*wv.z + xv[u].w*wv.w;
                }
                acc[rr] = a;
            }
        }
        __syncthreads();
    }

    // gelu + gate -> Hgs[token][r]
    {
        float g = gl[lane];
        #pragma unroll
        for (int rr = 0; rr < 16; ++rr) {
            float a = acc[rr];
            float h = 0.5f * a * (1.f + erff(a * 0.70710678118654752f));
            Hgs[lane * HG_STR + wu * 16 + rr] = g * h;
        }
    }
    __syncthreads();

    // ---------------- Phase B ----------------
    float hg[64];
    #pragma unroll
    for (int i = 0; i < 16; ++i) {
        float4 v = *reinterpret_cast<const float4*>(&Hgs[lane * HG_STR + 4 * i]);
        hg[4*i] = v.x; hg[4*i+1] = v.y; hg[4*i+2] = v.z; hg[4*i+3] = v.w;
    }

    float* Tr = &XsTr[wu * (64 * TR_STR)];   // per-wave 64x17 transpose buffer

    #pragma unroll 1
    for (int i = 0; i < 16; ++i) {
        const int dt    = wu + 4 * i;        // d-tile 0..63
        const int dbase = dt * 16;

        #pragma unroll 2
        for (int dd = 0; dd < 16; ++dd) {
            const float4* wr = reinterpret_cast<const float4*>(
                W2 + ((size_t)(e * DIMD + dbase + dd)) * RNK);   // uniform -> scalar
            float a0 = 0.f, a1 = 0.f;
            #pragma unroll
            for (int u = 0; u < 8; ++u) {
                float4 wv = wr[u];
                a0 += hg[4*u]*wv.x + hg[4*u+1]*wv.y + hg[4*u+2]*wv.z + hg[4*u+3]*wv.w;
            }
            #pragma unroll
            for (int u = 8; u < 16; ++u) {
                float4 wv = wr[u];
                a1 += hg[4*u]*wv.x + hg[4*u+1]*wv.y + hg[4*u+2]*wv.z + hg[4*u+3]*wv.w;
            }
            Tr[lane * TR_STR + dd] = a0 + a1;   // Y[token=lane][dd]
        }
        __syncthreads();   // uniform trip count for all waves -> safe

        // readback transposed + line-coalesced atomic scatter
        #pragma unroll 4
        for (int it2 = 0; it2 < 16; ++it2) {
            int tok = it2 * 4 + (lane >> 4);
            int dd  = lane & 15;
            float val = Tr[tok * TR_STR + dd];
            atomicAdd(out + (size_t)tokl[tok] * DIMD + dbase + dd, val);
        }
        __syncthreads();   // reads done before next iter overwrites Tr
    }
}

extern "C" void kernel_launch(void* const* d_in, const int* in_sizes, int n_in,
                              void* d_out, int out_size, void* d_ws, size_t ws_size,
                              hipStream_t stream) {
    const float* x  = (const float*)d_in[0];
    const float* Wg = (const float*)d_in[1];
    const float* bg = (const float*)d_in[2];
    const float* W1 = (const float*)d_in[3];
    const float* W2 = (const float*)d_in[4];
    float* out = (float*)d_out;

    const int N = in_sizes[0] / DIMD;        // 16384 tokens

    // ws layout: [0..31] counts, then lists (8*N int), then gates (8*N float)
    int*   counts = (int*)d_ws;
    int*   lists  = (int*)((char*)d_ws + 256);
    float* gates  = (float*)((char*)d_ws + 256 + (size_t)NEXP * N * sizeof(int));

    hipMemsetAsync(d_ws, 0, NEXP * sizeof(int), stream);                 // zero counts
    hipMemsetAsync(d_out, 0, (size_t)out_size * sizeof(float), stream);  // out accumulated via atomics

    const int rb = (N + 31) / 32;
    router_kernel<<<rb, 256, 0, stream>>>(x, Wg, bg, counts, lists, gates, N);

    const int EB = (N + 63) / 64;            // token tiles per expert
    expert_kernel<<<NEXP * EB, 256, 0, stream>>>(x, W1, W2, counts, lists, gates, out, N, EB);
}

// Round 4
// 407.108 us; speedup vs baseline: 4.7202x; 1.9966x over previous
//
#include <hip/hip_runtime.h>

#define DIMD 1024
#define NEXP 8
#define RNK  64
#define SCAL 2.0f
#define HG_STR 72   // 64 + 8 bf16 pad -> 144 B row stride (16B-aligned, 2-way banks = free)

typedef __attribute__((ext_vector_type(8))) short bf16x8;
typedef __attribute__((ext_vector_type(4))) float f32x4;

// f32 -> bf16 RTN (inputs are finite; no NaN guard needed)
__device__ __forceinline__ unsigned short f2bf(float f) {
    union { float f; unsigned int u; } v; v.f = f;
    return (unsigned short)((v.u + 0x7FFFu + ((v.u >> 16) & 1u)) >> 16);
}

__device__ __forceinline__ bf16x8 cvt8(float4 a, float4 b) {
    bf16x8 r;
    r[0] = (short)f2bf(a.x); r[1] = (short)f2bf(a.y);
    r[2] = (short)f2bf(a.z); r[3] = (short)f2bf(a.w);
    r[4] = (short)f2bf(b.x); r[5] = (short)f2bf(b.y);
    r[6] = (short)f2bf(b.z); r[7] = (short)f2bf(b.w);
    return r;
}

// ---------------- Kernel 0: W1/W2 f32 -> bf16 into ws ----------------
__global__ __launch_bounds__(256) void convert_w(
    const float* __restrict__ W1, const float* __restrict__ W2,
    unsigned short* __restrict__ W1b, unsigned short* __restrict__ W2b, int nW)
{
    int i = (blockIdx.x * 256 + threadIdx.x) * 4;
    if (i >= nW) return;
    float4 a = *reinterpret_cast<const float4*>(W1 + i);
    float4 b = *reinterpret_cast<const float4*>(W2 + i);
    ushort4 ua, ub;
    ua.x = f2bf(a.x); ua.y = f2bf(a.y); ua.z = f2bf(a.z); ua.w = f2bf(a.w);
    ub.x = f2bf(b.x); ub.y = f2bf(b.y); ub.z = f2bf(b.z); ub.w = f2bf(b.w);
    *reinterpret_cast<ushort4*>(W1b + i) = ua;
    *reinterpret_cast<ushort4*>(W2b + i) = ub;
}

// ---------------- Kernel 1: f32 router + per-expert token gather ------------
// 16 tokens/block, 4 per wave. Wg rows loaded once per wave and reused across
// the wave's 4 tokens; all x loads hoisted for ILP.
__global__ __launch_bounds__(256) void router_kernel(
    const float* __restrict__ x, const float* __restrict__ Wg,
    const float* __restrict__ bg,
    int* __restrict__ counts, int* __restrict__ lists, float* __restrict__ gates,
    int N)
{
    const int tid  = threadIdx.x;
    const int wu   = tid >> 6;
    const int lane = tid & 63;

    __shared__ int   lcount[NEXP];
    __shared__ int   gbase[NEXP];
    __shared__ int   tk_e[16][2];
    __shared__ int   tk_s[16][2];
    __shared__ float tk_g[16][2];

    if (tid < NEXP) lcount[tid] = 0;
    __syncthreads();

    const int t0 = blockIdx.x * 16;
    const int tb = wu * 4;

    // hoisted x loads: 4 tokens x 64B-per-lane
    float4 xv[4][4];
    #pragma unroll
    for (int it = 0; it < 4; ++it) {
        int t = t0 + tb + it; if (t > N - 1) t = N - 1;
        const float4* xp = reinterpret_cast<const float4*>(x + (size_t)t * DIMD + lane * 16);
        #pragma unroll
        for (int u = 0; u < 4; ++u) xv[it][u] = xp[u];
    }

    float acc[4][NEXP];
    #pragma unroll
    for (int it = 0; it < 4; ++it)
        #pragma unroll
        for (int e = 0; e < NEXP; ++e) acc[it][e] = 0.f;

    #pragma unroll
    for (int e = 0; e < NEXP; ++e) {
        const float4* wp = reinterpret_cast<const float4*>(Wg + (size_t)e * DIMD + lane * 16);
        float4 w0 = wp[0], w1 = wp[1], w2 = wp[2], w3 = wp[3];
        #pragma unroll
        for (int it = 0; it < 4; ++it) {
            acc[it][e] += xv[it][0].x*w0.x + xv[it][0].y*w0.y + xv[it][0].z*w0.z + xv[it][0].w*w0.w
                        + xv[it][1].x*w1.x + xv[it][1].y*w1.y + xv[it][1].z*w1.z + xv[it][1].w*w1.w
                        + xv[it][2].x*w2.x + xv[it][2].y*w2.y + xv[it][2].z*w2.z + xv[it][2].w*w2.w
                        + xv[it][3].x*w3.x + xv[it][3].y*w3.y + xv[it][3].z*w3.z + xv[it][3].w*w3.w;
        }
    }
    #pragma unroll
    for (int off = 32; off > 0; off >>= 1)
        #pragma unroll
        for (int it = 0; it < 4; ++it)
            #pragma unroll
            for (int e = 0; e < NEXP; ++e) acc[it][e] += __shfl_xor(acc[it][e], off);

    if (lane == 0) {
        for (int it = 0; it < 4; ++it) {
            int t = t0 + tb + it;
            if (t < N) {
                float lg[NEXP];
                #pragma unroll
                for (int e = 0; e < NEXP; ++e) lg[e] = acc[it][e] + bg[e];
                int e0 = 0;
                #pragma unroll
                for (int e = 1; e < NEXP; ++e) if (lg[e] > lg[e0]) e0 = e;
                int e1 = -1;
                #pragma unroll
                for (int e = 0; e < NEXP; ++e) {
                    if (e == e0) continue;
                    if (e1 < 0 || lg[e] > lg[e1]) e1 = e;
                }
                float g0 = 1.f / (1.f + expf(lg[e1] - lg[e0]));   // arg <= 0: stable
                int s0 = atomicAdd(&lcount[e0], 1);
                int s1 = atomicAdd(&lcount[e1], 1);
                int slot = tb + it;
                tk_e[slot][0] = e0; tk_s[slot][0] = s0; tk_g[slot][0] = g0 * SCAL;
                tk_e[slot][1] = e1; tk_s[slot][1] = s1; tk_g[slot][1] = (1.f - g0) * SCAL;
            }
        }
    }
    __syncthreads();
    if (tid < NEXP) gbase[tid] = atomicAdd(&counts[tid], lcount[tid]);
    __syncthreads();
    if (tid < 16 && (t0 + tid) < N) {
        #pragma unroll
        for (int k = 0; k < 2; ++k) {
            int e   = tk_e[tid][k];
            int pos = gbase[e] + tk_s[tid][k];
            lists[(size_t)e * N + pos] = t0 + tid;
            gates[(size_t)e * N + pos] = tk_g[tid][k];
        }
    }
}

// ---------------- Kernel 2: MFMA expert LoRA (fc1+gelu+fc2+scatter) ---------
// Block = (expert, 64-token tile), 256 threads (4 waves).
// GEMM1: wave w owns token strip [16w,16w+16); A = x rows (f32->bf16 on the
//        fly), B = W1b rows, 4 r-tiles, K=1024 (32 MFMA steps). Operands come
//        straight from global (weights L2-resident, x L3-resident) — no SMEM,
//        no lgkmcnt mixing (round-3's stall).
// Hg round-trip through LDS converts C-layout -> A-layout (m120 pattern).
// GEMM2: wave w owns d quarter [256w,256w+256); A = Hg (all 4 strips, 8 frags
//        in regs), B = W2b rows; coalesced atomicAdd scatter (64B per quad).
__global__ __launch_bounds__(256) void expert_kernel(
    const float* __restrict__ x,
    const unsigned short* __restrict__ W1b, const unsigned short* __restrict__ W2b,
    const int* __restrict__ counts, const int* __restrict__ lists,
    const float* __restrict__ gates, float* __restrict__ out, int N, int EB)
{
    const int e     = blockIdx.x / EB;
    const int jt    = blockIdx.x % EB;
    const int start = jt * 64;
    int m = counts[e] - start;
    if (m <= 0) return;
    if (m > 64) m = 64;

    const int tid  = threadIdx.x;
    const int wu   = __builtin_amdgcn_readfirstlane(tid >> 6);
    const int lane = tid & 63;
    const int l15  = lane & 15;
    const int q    = lane >> 4;

    __shared__ int            tokl[64];
    __shared__ float          gl[64];
    __shared__ unsigned short Hgs[64 * HG_STR];

    if (tid < 64) {
        int idx = (tid < m) ? (start + tid) : start;   // dummy -> tile's first token, gate 0
        tokl[tid] = lists[(size_t)e * N + idx];
        gl[tid]   = (tid < m) ? gates[(size_t)e * N + idx] : 0.f;
    }
    __syncthreads();

    // ---------------- GEMM1: H = X @ W1^T ----------------
    const float* xrow = x + (size_t)tokl[wu * 16 + l15] * DIMD + q * 8;
    const unsigned short* w1p = W1b + ((size_t)(e * RNK) + l15) * DIMD + q * 8;

    f32x4 acc[4];
    #pragma unroll
    for (int rt = 0; rt < 4; ++rt) acc[rt] = (f32x4){0.f, 0.f, 0.f, 0.f};

    #pragma unroll 4
    for (int ks = 0; ks < 32; ++ks) {
        const float4* xp = reinterpret_cast<const float4*>(xrow + ks * 32);
        float4 a0 = xp[0], a1 = xp[1];
        bf16x8 afrag = cvt8(a0, a1);
        #pragma unroll
        for (int rt = 0; rt < 4; ++rt) {
            bf16x8 b = *reinterpret_cast<const bf16x8*>(w1p + rt * 16 * DIMD + ks * 32);
            acc[rt] = __builtin_amdgcn_mfma_f32_16x16x32_bf16(afrag, b, acc[rt], 0, 0, 0);
        }
    }

    // epilogue: gelu + gate, C-layout (col=l15=r, row=q*4+reg=token) -> Hgs[token][r]
    {
        float gg[4];
        #pragma unroll
        for (int reg = 0; reg < 4; ++reg) gg[reg] = gl[wu * 16 + q * 4 + reg];
        #pragma unroll
        for (int rt = 0; rt < 4; ++rt) {
            #pragma unroll
            for (int reg = 0; reg < 4; ++reg) {
                float a = acc[rt][reg];
                float h = 0.5f * a * (1.f + erff(a * 0.70710678118654752f));
                Hgs[(wu * 16 + q * 4 + reg) * HG_STR + rt * 16 + l15] = f2bf(gg[reg] * h);
            }
        }
    }
    __syncthreads();

    // ---------------- GEMM2: Y = Hg @ W2^T ----------------
    // A-frags for all 4 token strips x 2 K-steps (K=64)
    bf16x8 a2[4][2];
    #pragma unroll
    for (int ts = 0; ts < 4; ++ts)
        #pragma unroll
        for (int ks = 0; ks < 2; ++ks)
            a2[ts][ks] = *reinterpret_cast<const bf16x8*>(
                &Hgs[(ts * 16 + l15) * HG_STR + ks * 32 + q * 8]);

    // per-lane output row pointers (token = ts*16 + q*4 + reg, d base = wu*256 + l15)
    float* rowp[4][4];
    #pragma unroll
    for (int ts = 0; ts < 4; ++ts)
        #pragma unroll
        for (int reg = 0; reg < 4; ++reg)
            rowp[ts][reg] = out + (size_t)tokl[ts * 16 + q * 4 + reg] * DIMD + wu * 256 + l15;

    const unsigned short* w2p = W2b + ((size_t)(e * DIMD + wu * 256) + l15) * RNK + q * 8;

    #pragma unroll 2
    for (int i = 0; i < 16; ++i) {
        bf16x8 b0 = *reinterpret_cast<const bf16x8*>(w2p + i * 16 * RNK);
        bf16x8 b1 = *reinterpret_cast<const bf16x8*>(w2p + i * 16 * RNK + 32);
        #pragma unroll
        for (int ts = 0; ts < 4; ++ts) {
            f32x4 c = (f32x4){0.f, 0.f, 0.f, 0.f};
            c = __builtin_amdgcn_mfma_f32_16x16x32_bf16(a2[ts][0], b0, c, 0, 0, 0);
            c = __builtin_amdgcn_mfma_f32_16x16x32_bf16(a2[ts][1], b1, c, 0, 0, 0);
            #pragma unroll
            for (int reg = 0; reg < 4; ++reg)
                atomicAdd(rowp[ts][reg] + i * 16, c[reg]);
        }
    }
}

extern "C" void kernel_launch(void* const* d_in, const int* in_sizes, int n_in,
                              void* d_out, int out_size, void* d_ws, size_t ws_size,
                              hipStream_t stream) {
    const float* x  = (const float*)d_in[0];
    const float* Wg = (const float*)d_in[1];
    const float* bg = (const float*)d_in[2];
    const float* W1 = (const float*)d_in[3];
    const float* W2 = (const float*)d_in[4];
    float* out = (float*)d_out;

    const int N = in_sizes[0] / DIMD;   // 16384 tokens

    // ws layout: counts (256 B) | lists 8N int | gates 8N f32 | W1b 1MB | W2b 1MB  (~3.1 MB)
    int*            counts = (int*)d_ws;
    int*            lists  = (int*)((char*)d_ws + 256);
    float*          gates  = (float*)((char*)d_ws + 256 + (size_t)NEXP * N * sizeof(int));
    unsigned short* W1b    = (unsigned short*)((char*)d_ws + 256 + (size_t)NEXP * N * 8);
    unsigned short* W2b    = W1b + (size_t)NEXP * RNK * DIMD;

    hipMemsetAsync(counts, 0, 256, stream);
    hipMemsetAsync(d_out, 0, (size_t)out_size * sizeof(float), stream);

    const int nW = NEXP * RNK * DIMD;   // 524288 each
    convert_w<<<(nW / 4 + 255) / 256, 256, 0, stream>>>(W1, W2, W1b, W2b, nW);

    router_kernel<<<(N + 15) / 16, 256, 0, stream>>>(x, Wg, bg, counts, lists, gates, N);

    const int EB = (N + 63) / 64;
    expert_kernel<<<NEXP * EB, 256, 0, stream>>>(x, W1b, W2b, counts, lists, gates, out, N, EB);
}

// Round 5
// 268.003 us; speedup vs baseline: 7.1702x; 1.5190x over previous
//
#include <hip/hip_runtime.h>

#define DIMD 1024
#define NEXP 8
#define RNK  64
#define SCAL 2.0f
#define HG_STR 72   // 64 + 8 bf16 pad

typedef __attribute__((ext_vector_type(8))) short bf16x8;
typedef __attribute__((ext_vector_type(4))) float f32x4;

__device__ __forceinline__ unsigned short f2bf(float f) {
    union { float f; unsigned int u; } v; v.f = f;
    return (unsigned short)((v.u + 0x7FFFu + ((v.u >> 16) & 1u)) >> 16);
}

__device__ __forceinline__ bf16x8 cvt8(float4 a, float4 b) {
    bf16x8 r;
    r[0] = (short)f2bf(a.x); r[1] = (short)f2bf(a.y);
    r[2] = (short)f2bf(a.z); r[3] = (short)f2bf(a.w);
    r[4] = (short)f2bf(b.x); r[5] = (short)f2bf(b.y);
    r[6] = (short)f2bf(b.z); r[7] = (short)f2bf(b.w);
    return r;
}

// ---------------- Kernel 0: W1/W2 f32 -> bf16 into ws ----------------
__global__ __launch_bounds__(256) void convert_w(
    const float* __restrict__ W1, const float* __restrict__ W2,
    unsigned short* __restrict__ W1b, unsigned short* __restrict__ W2b, int nW)
{
    int i = (blockIdx.x * 256 + threadIdx.x) * 4;
    if (i >= nW) return;
    float4 a = *reinterpret_cast<const float4*>(W1 + i);
    float4 b = *reinterpret_cast<const float4*>(W2 + i);
    ushort4 ua, ub;
    ua.x = f2bf(a.x); ua.y = f2bf(a.y); ua.z = f2bf(a.z); ua.w = f2bf(a.w);
    ub.x = f2bf(b.x); ub.y = f2bf(b.y); ub.z = f2bf(b.z); ub.w = f2bf(b.w);
    *reinterpret_cast<ushort4*>(W1b + i) = ua;
    *reinterpret_cast<ushort4*>(W2b + i) = ub;
}

// ---------------- Kernel 1: f32 router -> ordered-pair token lists ----------
// 16 tokens/block, 4/wave. Router math stays f32 (bf16 logits would flip
// ~1% of top-2 selections). Each token lands in exactly ONE pair list.
__global__ __launch_bounds__(256) void router_kernel(
    const float* __restrict__ x, const float* __restrict__ Wg,
    const float* __restrict__ bg,
    int* __restrict__ counts, int* __restrict__ plist, float* __restrict__ pgate,
    int N)
{
    const int tid  = threadIdx.x;
    const int wu   = tid >> 6;
    const int lane = tid & 63;

    __shared__ int   lcount[64];
    __shared__ int   gbase[64];
    __shared__ int   tk_p[16];
    __shared__ int   tk_s[16];
    __shared__ float tk_g[16];

    if (tid < 64) lcount[tid] = 0;
    __syncthreads();

    const int t0 = blockIdx.x * 16;
    const int tb = wu * 4;

    float4 xv[4][4];
    #pragma unroll
    for (int it = 0; it < 4; ++it) {
        int t = t0 + tb + it; if (t > N - 1) t = N - 1;
        const float4* xp = reinterpret_cast<const float4*>(x + (size_t)t * DIMD + lane * 16);
        #pragma unroll
        for (int u = 0; u < 4; ++u) xv[it][u] = xp[u];
    }

    float acc[4][NEXP];
    #pragma unroll
    for (int it = 0; it < 4; ++it)
        #pragma unroll
        for (int e = 0; e < NEXP; ++e) acc[it][e] = 0.f;

    #pragma unroll
    for (int e = 0; e < NEXP; ++e) {
        const float4* wp = reinterpret_cast<const float4*>(Wg + (size_t)e * DIMD + lane * 16);
        float4 w0 = wp[0], w1 = wp[1], w2 = wp[2], w3 = wp[3];
        #pragma unroll
        for (int it = 0; it < 4; ++it) {
            acc[it][e] += xv[it][0].x*w0.x + xv[it][0].y*w0.y + xv[it][0].z*w0.z + xv[it][0].w*w0.w
                        + xv[it][1].x*w1.x + xv[it][1].y*w1.y + xv[it][1].z*w1.z + xv[it][1].w*w1.w
                        + xv[it][2].x*w2.x + xv[it][2].y*w2.y + xv[it][2].z*w2.z + xv[it][2].w*w2.w
                        + xv[it][3].x*w3.x + xv[it][3].y*w3.y + xv[it][3].z*w3.z + xv[it][3].w*w3.w;
        }
    }
    #pragma unroll
    for (int off = 32; off > 0; off >>= 1)
        #pragma unroll
        for (int it = 0; it < 4; ++it)
            #pragma unroll
            for (int e = 0; e < NEXP; ++e) acc[it][e] += __shfl_xor(acc[it][e], off);

    if (lane == 0) {
        for (int it = 0; it < 4; ++it) {
            int t = t0 + tb + it;
            if (t < N) {
                float lg[NEXP];
                #pragma unroll
                for (int e = 0; e < NEXP; ++e) lg[e] = acc[it][e] + bg[e];
                int e0 = 0;
                #pragma unroll
                for (int e = 1; e < NEXP; ++e) if (lg[e] > lg[e0]) e0 = e;   // strict >: lower idx wins ties
                int e1 = -1;
                #pragma unroll
                for (int e = 0; e < NEXP; ++e) {
                    if (e == e0) continue;
                    if (e1 < 0 || lg[e] > lg[e1]) e1 = e;
                }
                float g0 = 1.f / (1.f + expf(lg[e1] - lg[e0]));   // arg <= 0: stable
                int p = e0 * 8 + e1;
                int s = atomicAdd(&lcount[p], 1);
                int slot = tb + it;
                tk_p[slot] = p; tk_s[slot] = s; tk_g[slot] = g0 * SCAL;
            }
        }
    }
    __syncthreads();
    if (tid < 64) gbase[tid] = atomicAdd(&counts[tid], lcount[tid]);
    __syncthreads();
    if (tid < 16 && (t0 + tid) < N) {
        int p   = tk_p[tid];
        int pos = gbase[p] + tk_s[tid];
        plist[(size_t)p * N + pos] = t0 + tid;
        pgate[(size_t)p * N + pos] = tk_g[tid];
    }
}

// ---------------- Kernel 1b: tiny scan (64 pair counts -> tile offsets) -----
__global__ void scan_kernel(const int* __restrict__ counts, int* __restrict__ tilestart) {
    if (threadIdx.x == 0) {
        int run = 0;
        for (int p = 0; p < 64; ++p) { tilestart[p] = run; run += (counts[p] + 15) >> 4; }
        tilestart[64] = run;
    }
}

// ---------------- Kernel 2: pair-grouped MFMA LoRA, atomic-free -------------
// Block = (pair (e0,e1), 16-token tile), 256 threads. GEMM1: wave=(expert h,
// r-half): H_h = gelu(X W1[e_h]^T)*gate_h, operands from global (weights
// L2-hot, x L1-shared across waves). Hg LDS round-trip (C->A layout, m120).
// GEMM2: wave owns 256 d; C-frag accumulates BOTH experts (K=64 each, 4 MFMA);
// plain coalesced f32 stores — each out row written exactly once.
__global__ __launch_bounds__(256) void pair_kernel(
    const float* __restrict__ x,
    const unsigned short* __restrict__ W1b, const unsigned short* __restrict__ W2b,
    const int* __restrict__ counts, const int* __restrict__ tilestart,
    const int* __restrict__ plist, const float* __restrict__ pgate,
    float* __restrict__ out, int N)
{
    const int tid = threadIdx.x;

    __shared__ int ts[65];
    __shared__ int tokl[16];
    __shared__ float gA[16], gB[16];
    __shared__ __align__(16) unsigned short Hgs[2][16 * HG_STR];

    if (tid < 65) ts[tid] = tilestart[tid];
    __syncthreads();

    const int b = blockIdx.x;
    if (b >= ts[64]) return;

    int lo = 0, hi = 64;                      // binary search: ts[p] <= b < ts[p+1]
    while (hi - lo > 1) { int mid = (lo + hi) >> 1; if (ts[mid] <= b) lo = mid; else hi = mid; }
    const int p  = lo;
    const int e0 = p >> 3, e1 = p & 7;
    const int start = (b - ts[p]) * 16;
    int m = counts[p] - start; if (m > 16) m = 16;

    if (tid < 16) {
        int idx = start + ((tid < m) ? tid : 0);     // pad -> tile's first token, gate 0
        tokl[tid] = plist[(size_t)p * N + idx];
        float g = (tid < m) ? pgate[(size_t)p * N + idx] : 0.f;
        gA[tid] = g;
        gB[tid] = (tid < m) ? (SCAL - g) : 0.f;      // (1-g0)*SCAL
    }
    __syncthreads();

    const int wu   = __builtin_amdgcn_readfirstlane(tid >> 6);
    const int lane = tid & 63;
    const int l15  = lane & 15;
    const int q    = lane >> 4;
    const int h    = wu >> 1;          // which expert of the pair
    const int rh   = wu & 1;           // which r-half
    const int eh   = h ? e1 : e0;

    // ---------------- GEMM1 ----------------
    const float* xrow = x + (size_t)tokl[l15] * DIMD + q * 8;
    const unsigned short* w1p = W1b + ((size_t)(eh * RNK + rh * 32) + l15) * DIMD + q * 8;

    f32x4 acc0 = (f32x4){0.f,0.f,0.f,0.f}, acc1 = (f32x4){0.f,0.f,0.f,0.f};
    #pragma unroll 4
    for (int ks = 0; ks < 32; ++ks) {
        const float4* xp = reinterpret_cast<const float4*>(xrow + ks * 32);
        float4 a0 = xp[0], a1 = xp[1];
        bf16x8 afrag = cvt8(a0, a1);
        bf16x8 b0 = *reinterpret_cast<const bf16x8*>(w1p + ks * 32);
        bf16x8 b1 = *reinterpret_cast<const bf16x8*>(w1p + 16 * DIMD + ks * 32);
        acc0 = __builtin_amdgcn_mfma_f32_16x16x32_bf16(afrag, b0, acc0, 0, 0, 0);
        acc1 = __builtin_amdgcn_mfma_f32_16x16x32_bf16(afrag, b1, acc1, 0, 0, 0);
    }

    // epilogue: C-layout row = q*4+reg = token, col = l15 = r (within half)
    {
        const float* gh = h ? gB : gA;
        #pragma unroll
        for (int reg = 0; reg < 4; ++reg) {
            int row = q * 4 + reg;
            float g = gh[row];
            float a = acc0[reg];
            float v = 0.5f * a * (1.f + erff(a * 0.70710678118654752f));
            Hgs[h][row * HG_STR + rh * 32 + l15] = f2bf(g * v);
            a = acc1[reg];
            v = 0.5f * a * (1.f + erff(a * 0.70710678118654752f));
            Hgs[h][row * HG_STR + rh * 32 + 16 + l15] = f2bf(g * v);
        }
    }
    __syncthreads();

    // ---------------- GEMM2 ----------------
    bf16x8 a00 = *reinterpret_cast<const bf16x8*>(&Hgs[0][l15 * HG_STR + q * 8]);
    bf16x8 a01 = *reinterpret_cast<const bf16x8*>(&Hgs[0][l15 * HG_STR + 32 + q * 8]);
    bf16x8 a10 = *reinterpret_cast<const bf16x8*>(&Hgs[1][l15 * HG_STR + q * 8]);
    bf16x8 a11 = *reinterpret_cast<const bf16x8*>(&Hgs[1][l15 * HG_STR + 32 + q * 8]);

    const unsigned short* w2p0 = W2b + ((size_t)(e0 * DIMD + wu * 256) + l15) * RNK + q * 8;
    const unsigned short* w2p1 = W2b + ((size_t)(e1 * DIMD + wu * 256) + l15) * RNK + q * 8;
    const int dbase = wu * 256 + l15;

    #pragma unroll 4
    for (int i = 0; i < 16; ++i) {
        bf16x8 b00 = *reinterpret_cast<const bf16x8*>(w2p0 + i * 16 * RNK);
        bf16x8 b01 = *reinterpret_cast<const bf16x8*>(w2p0 + i * 16 * RNK + 32);
        bf16x8 b10 = *reinterpret_cast<const bf16x8*>(w2p1 + i * 16 * RNK);
        bf16x8 b11 = *reinterpret_cast<const bf16x8*>(w2p1 + i * 16 * RNK + 32);
        f32x4 c = (f32x4){0.f,0.f,0.f,0.f};
        c = __builtin_amdgcn_mfma_f32_16x16x32_bf16(a00, b00, c, 0, 0, 0);
        c = __builtin_amdgcn_mfma_f32_16x16x32_bf16(a01, b01, c, 0, 0, 0);
        c = __builtin_amdgcn_mfma_f32_16x16x32_bf16(a10, b10, c, 0, 0, 0);
        c = __builtin_amdgcn_mfma_f32_16x16x32_bf16(a11, b11, c, 0, 0, 0);
        #pragma unroll
        for (int reg = 0; reg < 4; ++reg) {
            int row = q * 4 + reg;
            if (row < m)
                out[(size_t)tokl[row] * DIMD + dbase + i * 16] = c[reg];
        }
    }
}

extern "C" void kernel_launch(void* const* d_in, const int* in_sizes, int n_in,
                              void* d_out, int out_size, void* d_ws, size_t ws_size,
                              hipStream_t stream) {
    const float* x  = (const float*)d_in[0];
    const float* Wg = (const float*)d_in[1];
    const float* bg = (const float*)d_in[2];
    const float* W1 = (const float*)d_in[3];
    const float* W2 = (const float*)d_in[4];
    float* out = (float*)d_out;

    const int N = in_sizes[0] / DIMD;   // 16384 tokens

    // ws: counts[64] | tilestart[65] (pad to 1 KB) | W1b 1MB | W2b 1MB |
    //     plist 64*N int (4MB) | pgate 64*N f32 (4MB)   => ~10.5 MB
    int*            counts    = (int*)d_ws;
    int*            tilestart = (int*)((char*)d_ws + 256);
    unsigned short* W1b       = (unsigned short*)((char*)d_ws + 1024);
    unsigned short* W2b       = W1b + (size_t)NEXP * RNK * DIMD;
    int*            plist     = (int*)((char*)d_ws + 1024 + 2u * NEXP * RNK * DIMD * sizeof(unsigned short));
    float*          pgate     = (float*)(plist + (size_t)64 * N);

    hipMemsetAsync(counts, 0, 256, stream);   // no out memset: pair kernel fully covers out

    const int nW = NEXP * RNK * DIMD;
    convert_w<<<(nW / 4 + 255) / 256, 256, 0, stream>>>(W1, W2, W1b, W2b, nW);

    router_kernel<<<(N + 15) / 16, 256, 0, stream>>>(x, Wg, bg, counts, plist, pgate, N);
    scan_kernel<<<1, 64, 0, stream>>>(counts, tilestart);

    const int maxTiles = (N + 15) / 16 + 56;
    pair_kernel<<<maxTiles, 256, 0, stream>>>(x, W1b, W2b, counts, tilestart, plist, pgate, out, N);
}